// Round 1
// baseline (78.442 us; speedup 1.0000x reference)
//
#include <hip/hip_runtime.h>

// LCALayer: per-row (N=2e6, D=8) elementwise update.
// recur = sum(activities @ gamma) where gamma = -0.1 off-diag, 0 diag
//       = -0.1 * (8*S - S) = -0.7 * S,  S = row-sum of activities.
// active = all(|activities| < 1) ? 1 : 0
// pre = pa + (inp - 0.1*pa + recur) * active * 0.01 + nr * active * sqrt(0.001)
// act = relu(pre)

#define THRESHOLD 1.0f
#define LEAK 0.1f
#define TSTEP 0.01f
#define SQRT_STEP 0.031622776601683794f  // sqrt(0.001)

__global__ __launch_bounds__(256) void lca_kernel(
    const float* __restrict__ inp,
    const float* __restrict__ pa,
    const float* __restrict__ acts,
    const float* __restrict__ nr,
    float* __restrict__ out_pre,
    float* __restrict__ out_act,
    float* __restrict__ out_active,
    int n)
{
    const int stride = gridDim.x * blockDim.x;
    for (int row = blockIdx.x * blockDim.x + threadIdx.x; row < n; row += stride) {
        const size_t base = (size_t)row * 8;

        // --- activities: active mask + row sum ---
        float4 a0 = *reinterpret_cast<const float4*>(acts + base);
        float4 a1 = *reinterpret_cast<const float4*>(acts + base + 4);
        float a[8] = {a0.x, a0.y, a0.z, a0.w, a1.x, a1.y, a1.z, a1.w};

        bool all_below = true;
        float S = 0.0f;
#pragma unroll
        for (int j = 0; j < 8; ++j) {
            all_below = all_below && (fabsf(a[j]) < THRESHOLD);
            S += a[j];
        }
        const float active = all_below ? 1.0f : 0.0f;
        const float recur = -0.7f * S;

        // --- other inputs ---
        float4 i0 = *reinterpret_cast<const float4*>(inp + base);
        float4 i1 = *reinterpret_cast<const float4*>(inp + base + 4);
        float4 p0 = *reinterpret_cast<const float4*>(pa + base);
        float4 p1 = *reinterpret_cast<const float4*>(pa + base + 4);
        float4 n0 = *reinterpret_cast<const float4*>(nr + base);
        float4 n1 = *reinterpret_cast<const float4*>(nr + base + 4);

        float iv[8] = {i0.x, i0.y, i0.z, i0.w, i1.x, i1.y, i1.z, i1.w};
        float pv[8] = {p0.x, p0.y, p0.z, p0.w, p1.x, p1.y, p1.z, p1.w};
        float nv[8] = {n0.x, n0.y, n0.z, n0.w, n1.x, n1.y, n1.z, n1.w};

        const float ts_a = active * TSTEP;       // (x * active) * 0.01
        const float ns_a = active * SQRT_STEP;   // noise scale

        float pr[8], ac[8];
#pragma unroll
        for (int j = 0; j < 8; ++j) {
            float x = iv[j] - LEAK * pv[j] + recur;
            float p = pv[j] + x * ts_a;
            p = p + nv[j] * ns_a;
            pr[j] = p;
            ac[j] = fmaxf(p, 0.0f);
        }

        float4 pr0 = {pr[0], pr[1], pr[2], pr[3]};
        float4 pr1 = {pr[4], pr[5], pr[6], pr[7]};
        float4 ac0 = {ac[0], ac[1], ac[2], ac[3]};
        float4 ac1 = {ac[4], ac[5], ac[6], ac[7]};

        *reinterpret_cast<float4*>(out_pre + base)     = pr0;
        *reinterpret_cast<float4*>(out_pre + base + 4) = pr1;
        *reinterpret_cast<float4*>(out_act + base)     = ac0;
        *reinterpret_cast<float4*>(out_act + base + 4) = ac1;
        out_active[row] = active;
    }
}

extern "C" void kernel_launch(void* const* d_in, const int* in_sizes, int n_in,
                              void* d_out, int out_size, void* d_ws, size_t ws_size,
                              hipStream_t stream) {
    const float* inp  = (const float*)d_in[0];
    const float* pa   = (const float*)d_in[1];
    const float* acts = (const float*)d_in[2];
    const float* nr   = (const float*)d_in[3];

    const int n = in_sizes[0] / 8;  // 2,000,000 rows

    float* out = (float*)d_out;
    float* out_pre    = out;                    // [n, 8]
    float* out_act    = out + (size_t)n * 8;    // [n, 8]
    float* out_active = out + (size_t)n * 16;   // [n, 1]

    const int block = 256;
    const int grid = 2048;  // grid-stride; 256 CU * 8 blocks/CU
    lca_kernel<<<grid, block, 0, stream>>>(inp, pa, acts, nr,
                                           out_pre, out_act, out_active, n);
}

// Round 3
// 72.676 us; speedup vs baseline: 1.0793x; 1.0793x over previous
//
#include <hip/hip_runtime.h>

// LCALayer: per-row (N=2e6, D=8) elementwise update.
// recur = sum(activities @ gamma) where gamma = -0.1 off-diag, 0 diag
//       = -0.1 * (8*S - S) = -0.7 * S,  S = row-sum of activities.
// active = all(|activities| < 1) ? 1 : 0
// pre = pa + (inp - 0.1*pa + recur) * active * 0.01 + nr * active * sqrt(0.001)
// act = relu(pre)
//
// R2: non-temporal stores via native clang vector type (HIP float4 is a
// struct and rejected by __builtin_nontemporal_store). Outputs are never
// re-read -> bypass cache, keep the 256MB input set L3-resident.

#define THRESHOLD 1.0f
#define LEAK 0.1f
#define TSTEP 0.01f
#define SQRT_STEP 0.031622776601683794f  // sqrt(0.001)

typedef float vfloat4 __attribute__((ext_vector_type(4)));

__global__ __launch_bounds__(256) void lca_kernel(
    const float* __restrict__ inp,
    const float* __restrict__ pa,
    const float* __restrict__ acts,
    const float* __restrict__ nr,
    float* __restrict__ out_pre,
    float* __restrict__ out_act,
    float* __restrict__ out_active,
    int n)
{
    const int row = blockIdx.x * blockDim.x + threadIdx.x;
    if (row >= n) return;
    const size_t base = (size_t)row * 8;

    // --- issue all loads up front (max memory-level parallelism) ---
    vfloat4 a0 = *reinterpret_cast<const vfloat4*>(acts + base);
    vfloat4 a1 = *reinterpret_cast<const vfloat4*>(acts + base + 4);
    vfloat4 i0 = *reinterpret_cast<const vfloat4*>(inp + base);
    vfloat4 i1 = *reinterpret_cast<const vfloat4*>(inp + base + 4);
    vfloat4 p0 = *reinterpret_cast<const vfloat4*>(pa + base);
    vfloat4 p1 = *reinterpret_cast<const vfloat4*>(pa + base + 4);
    vfloat4 n0 = *reinterpret_cast<const vfloat4*>(nr + base);
    vfloat4 n1 = *reinterpret_cast<const vfloat4*>(nr + base + 4);

    float a[8] = {a0.x, a0.y, a0.z, a0.w, a1.x, a1.y, a1.z, a1.w};

    bool all_below = true;
    float S = 0.0f;
#pragma unroll
    for (int j = 0; j < 8; ++j) {
        all_below = all_below && (fabsf(a[j]) < THRESHOLD);
        S += a[j];
    }
    const float active = all_below ? 1.0f : 0.0f;
    const float recur = -0.7f * S;

    float iv[8] = {i0.x, i0.y, i0.z, i0.w, i1.x, i1.y, i1.z, i1.w};
    float pv[8] = {p0.x, p0.y, p0.z, p0.w, p1.x, p1.y, p1.z, p1.w};
    float nv[8] = {n0.x, n0.y, n0.z, n0.w, n1.x, n1.y, n1.z, n1.w};

    const float ts_a = active * TSTEP;       // (x * active) * 0.01
    const float ns_a = active * SQRT_STEP;   // noise scale

    float pr[8], ac[8];
#pragma unroll
    for (int j = 0; j < 8; ++j) {
        float x = iv[j] - LEAK * pv[j] + recur;
        float p = pv[j] + x * ts_a;
        p = p + nv[j] * ns_a;
        pr[j] = p;
        ac[j] = fmaxf(p, 0.0f);
    }

    vfloat4 pr0 = {pr[0], pr[1], pr[2], pr[3]};
    vfloat4 pr1 = {pr[4], pr[5], pr[6], pr[7]};
    vfloat4 ac0 = {ac[0], ac[1], ac[2], ac[3]};
    vfloat4 ac1 = {ac[4], ac[5], ac[6], ac[7]};

    // non-temporal stores: bypass cache, keep inputs L3-resident
    __builtin_nontemporal_store(pr0, reinterpret_cast<vfloat4*>(out_pre + base));
    __builtin_nontemporal_store(pr1, reinterpret_cast<vfloat4*>(out_pre + base + 4));
    __builtin_nontemporal_store(ac0, reinterpret_cast<vfloat4*>(out_act + base));
    __builtin_nontemporal_store(ac1, reinterpret_cast<vfloat4*>(out_act + base + 4));
    __builtin_nontemporal_store(active, out_active + row);
}

extern "C" void kernel_launch(void* const* d_in, const int* in_sizes, int n_in,
                              void* d_out, int out_size, void* d_ws, size_t ws_size,
                              hipStream_t stream) {
    const float* inp  = (const float*)d_in[0];
    const float* pa   = (const float*)d_in[1];
    const float* acts = (const float*)d_in[2];
    const float* nr   = (const float*)d_in[3];

    const int n = in_sizes[0] / 8;  // 2,000,000 rows

    float* out = (float*)d_out;
    float* out_pre    = out;                    // [n, 8]
    float* out_act    = out + (size_t)n * 8;    // [n, 8]
    float* out_active = out + (size_t)n * 16;   // [n, 1]

    const int block = 256;
    const int grid = (n + block - 1) / block;   // one thread per row
    lca_kernel<<<grid, block, 0, stream>>>(inp, pa, acts, nr,
                                           out_pre, out_act, out_active, n);
}